// Round 11
// baseline (67.160 us; speedup 1.0000x reference)
//
#include <hip/hip_runtime.h>
#include <hip/hip_bf16.h>
#include <math.h>

// max_{n,m} ||L[n]-R[m]||, L,R: [8192][64] fp32.
// R11: MEASUREMENT ROUND. R10 structure with the compute loop (MFMA+epilogue)
// repeated 8x via a non-unrolled loop + "memory" clobber (forces genuine
// re-execution; atomicMax idempotent). Purpose: push the main dispatch past
// the ~39us poison fills so rocprof top-5 finally shows its counters, and/or
// back out compute-vs-stage split from total: total ~= 23.3 + 7*compute.

typedef __attribute__((ext_vector_type(8)))  short  short8;   // bf16x8 frag
typedef __attribute__((ext_vector_type(4)))  float  f32x4;
typedef __attribute__((ext_vector_type(16))) float  f32x16;   // 32x32 accum

constexpr int D  = 64;
constexpr int NR = 8192;
constexpr int REP = 8;

__device__ __forceinline__ short f2bf(float f) {
    __hip_bfloat16 h = __float2bfloat16(f);
    return __builtin_bit_cast(short, h);
}

// Frag-packed layout: row r, k-chunk kk (16 k's), k-half kh, elem e:
//   short index = ((r>>5)*4 + kk)*512 + (kh*32 + (r&31))*8 + e

__global__ __launch_bounds__(256) void prepack_kernel(
    const float* __restrict__ L, const float* __restrict__ R,
    short* __restrict__ Apk, short* __restrict__ Bpk,
    float* __restrict__ lsq, float* __restrict__ rsq,
    unsigned int* __restrict__ outbits)
{
    const int t = blockIdx.x * 256 + threadIdx.x;   // 0..131071
    const int r = t >> 3;
    const int j = t & 7;
    const int kk = j >> 1, kh = j & 1;
    const bool isL = (r < NR);
    const int rr = isL ? r : r - NR;

    const float* src = (isL ? L : R) + (size_t)rr * D + j * 8;
    short* pk = isL ? Apk : Bpk;

    f32x4 v0 = *reinterpret_cast<const f32x4*>(src + 0);
    f32x4 v1 = *reinterpret_cast<const f32x4*>(src + 4);

    float p = 0.f;
    #pragma unroll
    for (int e = 0; e < 4; ++e) { p = fmaf(v0[e], v0[e], p); p = fmaf(v1[e], v1[e], p); }

    short8 w;
    #pragma unroll
    for (int e = 0; e < 4; ++e) { w[e] = f2bf(v0[e]); w[4+e] = f2bf(v1[e]); }
    *reinterpret_cast<short8*>(
        pk + ((size_t)(rr >> 5) * 4 + kk) * 512 + (kh * 32 + (rr & 31)) * 8) = w;

    p += __shfl_xor(p, 1, 64);
    p += __shfl_xor(p, 2, 64);
    p += __shfl_xor(p, 4, 64);
    if (j == 0) (isL ? lsq : rsq)[rr] = p;

    if (t == 0) *outbits = 0u;
}

// ---- main: R10 structure, compute repeated REP times ----
__global__ __launch_bounds__(256, 2) void pairdist_mfma_kernel(
    const short* __restrict__ Apk, const short* __restrict__ Bpk,
    const float* __restrict__ lsq, const float* __restrict__ rsq,
    unsigned int* __restrict__ outbits)
{
    __shared__ __align__(16) short A_lds[16][4][64][8];   // 64 KiB

    const int tid  = threadIdx.x;
    const int lane = tid & 63;
    const int wave = tid >> 6;
    const int xc = blockIdx.x;
    const int yb = blockIdx.y;

    {
        const short* At = Apk + (size_t)(xc * 16) * 2048;
        short* Al = &A_lds[0][0][0][0];
        #pragma unroll
        for (int i = 0; i < 16; ++i) {
            const int off = (i * 4 + wave) * 512;
            __builtin_amdgcn_global_load_lds(
                (const __attribute__((address_space(1))) unsigned int*)(At + off + lane * 8),
                (__attribute__((address_space(3))) unsigned int*)(Al + off),
                16, 0, 0);
        }
    }

    const int wm = wave >> 1;
    const int wn = wave & 1;
    short8 bf[4][4];
    #pragma unroll
    for (int nj = 0; nj < 4; ++nj)
        #pragma unroll
        for (int kk = 0; kk < 4; ++kk)
            bf[nj][kk] = *reinterpret_cast<const short8*>(
                Bpk + ((size_t)(yb * 8 + wn * 4 + nj) * 4 + kk) * 512 + lane * 8);

    const int col = lane & 31;
    const int h   = lane >> 5;
    float rq[4];
    #pragma unroll
    for (int nj = 0; nj < 4; ++nj)
        rq[nj] = rsq[yb * 256 + wn * 128 + nj * 32 + col];

    __syncthreads();   // A staged

    float lmax = 0.f;
    #pragma unroll 1
    for (int rep = 0; rep < REP; ++rep) {
        asm volatile("" ::: "memory");   // force genuine re-execution each rep
        #pragma unroll
        for (int t = 0; t < 4; ++t) {
            f32x4 lqv[2][4];
            #pragma unroll
            for (int mi = 0; mi < 2; ++mi) {
                const int rbase = xc * 512 + t * 128 + (wm * 2 + mi) * 32 + 4 * h;
                #pragma unroll
                for (int g = 0; g < 4; ++g)
                    lqv[mi][g] = *reinterpret_cast<const f32x4*>(lsq + rbase + g * 8);
            }

            f32x16 acc[2][4] = {};
            #pragma unroll
            for (int kk = 0; kk < 4; ++kk) {
                short8 a0 = *reinterpret_cast<const short8*>(&A_lds[t*4 + wm*2 + 0][kk][lane][0]);
                short8 a1 = *reinterpret_cast<const short8*>(&A_lds[t*4 + wm*2 + 1][kk][lane][0]);
                acc[0][0] = __builtin_amdgcn_mfma_f32_32x32x16_bf16(a0, bf[0][kk], acc[0][0], 0, 0, 0);
                acc[0][1] = __builtin_amdgcn_mfma_f32_32x32x16_bf16(a0, bf[1][kk], acc[0][1], 0, 0, 0);
                acc[0][2] = __builtin_amdgcn_mfma_f32_32x32x16_bf16(a0, bf[2][kk], acc[0][2], 0, 0, 0);
                acc[0][3] = __builtin_amdgcn_mfma_f32_32x32x16_bf16(a0, bf[3][kk], acc[0][3], 0, 0, 0);
                acc[1][0] = __builtin_amdgcn_mfma_f32_32x32x16_bf16(a1, bf[0][kk], acc[1][0], 0, 0, 0);
                acc[1][1] = __builtin_amdgcn_mfma_f32_32x32x16_bf16(a1, bf[1][kk], acc[1][1], 0, 0, 0);
                acc[1][2] = __builtin_amdgcn_mfma_f32_32x32x16_bf16(a1, bf[2][kk], acc[1][2], 0, 0, 0);
                acc[1][3] = __builtin_amdgcn_mfma_f32_32x32x16_bf16(a1, bf[3][kk], acc[1][3], 0, 0, 0);
            }

            #pragma unroll
            for (int mi = 0; mi < 2; ++mi) {
                #pragma unroll
                for (int nj = 0; nj < 4; ++nj) {
                    float x[16];
                    #pragma unroll
                    for (int g = 0; g < 4; ++g)
                        #pragma unroll
                        for (int e = 0; e < 4; ++e)
                            x[g*4+e] = fmaf(-2.f, acc[mi][nj][g*4 + e], lqv[mi][g][e]);
                    float y0 = fmaxf(x[0],  x[1]),  y1 = fmaxf(x[2],  x[3]);
                    float y2 = fmaxf(x[4],  x[5]),  y3 = fmaxf(x[6],  x[7]);
                    float y4 = fmaxf(x[8],  x[9]),  y5 = fmaxf(x[10], x[11]);
                    float y6 = fmaxf(x[12], x[13]), y7 = fmaxf(x[14], x[15]);
                    float z0 = fmaxf(y0, y1), z1 = fmaxf(y2, y3);
                    float z2 = fmaxf(y4, y5), z3 = fmaxf(y6, y7);
                    float m  = fmaxf(fmaxf(z0, z1), fmaxf(z2, z3));
                    lmax = fmaxf(lmax, m + rq[nj]);
                }
            }
        }
    }

    #pragma unroll
    for (int off = 32; off >= 1; off >>= 1)
        lmax = fmaxf(lmax, __shfl_xor(lmax, off, 64));

    __syncthreads();
    float* wmax = reinterpret_cast<float*>(&A_lds[0][0][0][0]);
    if (lane == 0) wmax[wave] = lmax;
    __syncthreads();
    if (tid == 0) {
        float bmax = fmaxf(fmaxf(wmax[0], wmax[1]), fmaxf(wmax[2], wmax[3]));
        bmax = sqrtf(fmaxf(bmax, 0.f));
        atomicMax(outbits, __float_as_uint(bmax));
    }
}

extern "C" void kernel_launch(void* const* d_in, const int* in_sizes, int n_in,
                              void* d_out, int out_size, void* d_ws, size_t ws_size,
                              hipStream_t stream) {
    const float* L = (const float*)d_in[0];
    const float* R = (const float*)d_in[1];

    short* Apk = (short*)d_ws;
    short* Bpk = Apk + (size_t)NR * D;
    float* lsqg = (float*)(Bpk + (size_t)NR * D);
    float* rsqg = lsqg + NR;
    unsigned int* outbits = (unsigned int*)d_out;

    prepack_kernel<<<(2 * NR * 8) / 256, 256, 0, stream>>>(L, R, Apk, Bpk, lsqg, rsqg, outbits);
    pairdist_mfma_kernel<<<dim3(16, 32), dim3(256), 0, stream>>>(Apk, Bpk, lsqg, rsqg, outbits);
}

// Round 12
// 60.358 us; speedup vs baseline: 1.1127x; 1.1127x over previous
//
#include <hip/hip_runtime.h>
#include <hip/hip_bf16.h>
#include <math.h>

// max_{n,m} ||L[n]-R[m]||, L,R: [8192][64] fp32.
// R12: occupancy-first redesign from R11 counters (MfmaUtil 45 / VALU 45 /
// occ 16.7% / stage ~13us exposed). Wave tile 64x64: acc[2][2]=64 AGPR,
// bf[2][4]=32 VGPR -> ~120 live regs -> 4 waves/SIMD (2x R11). Block 128x128,
// A_lds 16KB, grid 4096 (4+ resident/CU -> block-level pipelining hides the
// stage drain). XCD-swizzle: xc = bid&63 so same-A blocks share an XCD L2.

typedef __attribute__((ext_vector_type(8)))  short  short8;   // bf16x8 frag
typedef __attribute__((ext_vector_type(4)))  float  f32x4;
typedef __attribute__((ext_vector_type(16))) float  f32x16;   // 32x32 accum

constexpr int D  = 64;
constexpr int NR = 8192;

__device__ __forceinline__ short f2bf(float f) {
    __hip_bfloat16 h = __float2bfloat16(f);
    return __builtin_bit_cast(short, h);
}

// Frag-packed layout: row r, k-chunk kk (16 k's), k-half kh, elem e:
//   short index = ((r>>5)*4 + kk)*512 + (kh*32 + (r&31))*8 + e

__global__ __launch_bounds__(256) void prepack_kernel(
    const float* __restrict__ L, const float* __restrict__ R,
    short* __restrict__ Apk, short* __restrict__ Bpk,
    float* __restrict__ lsq, float* __restrict__ rsq,
    unsigned int* __restrict__ outbits)
{
    const int t = blockIdx.x * 256 + threadIdx.x;   // 0..131071
    const int r = t >> 3;
    const int j = t & 7;
    const int kk = j >> 1, kh = j & 1;
    const bool isL = (r < NR);
    const int rr = isL ? r : r - NR;

    const float* src = (isL ? L : R) + (size_t)rr * D + j * 8;
    short* pk = isL ? Apk : Bpk;

    f32x4 v0 = *reinterpret_cast<const f32x4*>(src + 0);
    f32x4 v1 = *reinterpret_cast<const f32x4*>(src + 4);

    float p = 0.f;
    #pragma unroll
    for (int e = 0; e < 4; ++e) { p = fmaf(v0[e], v0[e], p); p = fmaf(v1[e], v1[e], p); }

    short8 w;
    #pragma unroll
    for (int e = 0; e < 4; ++e) { w[e] = f2bf(v0[e]); w[4+e] = f2bf(v1[e]); }
    *reinterpret_cast<short8*>(
        pk + ((size_t)(rr >> 5) * 4 + kk) * 512 + (kh * 32 + (rr & 31)) * 8) = w;

    p += __shfl_xor(p, 1, 64);
    p += __shfl_xor(p, 2, 64);
    p += __shfl_xor(p, 4, 64);
    if (j == 0) (isL ? lsq : rsq)[rr] = p;

    if (t == 0) *outbits = 0u;   // zero d_out (harness poisons 0xAA)
}

// ---- main: 4 waves (2m x 2n), block 128m x 128n one-shot ----
// grid 4096 1-D: xc = bid & 63 (rows), yb = bid >> 6 (cols).
// Same-xc blocks have equal bid%8 -> land on the same XCD (L2 shares A chunk).
__global__ __launch_bounds__(256, 4) void pairdist_mfma_kernel(
    const short* __restrict__ Apk, const short* __restrict__ Bpk,
    const float* __restrict__ lsq, const float* __restrict__ rsq,
    unsigned int* __restrict__ outbits)
{
    __shared__ __align__(16) short A_lds[4][4][64][8];   // 16 KiB (128 rows)
    __shared__ float wmax_s[4];

    const int tid  = threadIdx.x;
    const int lane = tid & 63;
    const int wave = tid >> 6;
    const int bid  = blockIdx.x;
    const int xc = bid & 63;       // row chunk (128 rows)
    const int yb = bid >> 6;       // col chunk (128 cols)

    // ---- stage A (16 x 1KB global_load_lds): wave = kk, i = row group ----
    {
        const short* At = Apk + (size_t)(xc * 4) * 2048;
        #pragma unroll
        for (int i = 0; i < 4; ++i)
            __builtin_amdgcn_global_load_lds(
                (const __attribute__((address_space(1))) unsigned int*)
                    (At + ((size_t)i * 4 + wave) * 512 + lane * 8),
                (__attribute__((address_space(3))) unsigned int*)
                    (&A_lds[i][wave][0][0]),
                16, 0, 0);
    }

    const int wm = wave >> 1;      // 64-row half of 128
    const int wn = wave & 1;       // 64-col half of 128
    // ---- B-frags (2 col groups x 4 kk = 8 dwordx4, 32 VGPR) ----
    short8 bf[2][4];
    #pragma unroll
    for (int nj = 0; nj < 2; ++nj)
        #pragma unroll
        for (int kk = 0; kk < 4; ++kk)
            bf[nj][kk] = *reinterpret_cast<const short8*>(
                Bpk + ((size_t)(yb * 4 + wn * 2 + nj) * 4 + kk) * 512 + lane * 8);

    const int col = lane & 31;
    const int h   = lane >> 5;
    float rq[2];
    #pragma unroll
    for (int nj = 0; nj < 2; ++nj)
        rq[nj] = rsq[yb * 128 + (wn * 2 + nj) * 32 + col];

    __syncthreads();   // A staged (vmcnt drained by compiler)

    // ---- MFMA: acc[2][2] (64 AGPR), 16 MFMAs ----
    f32x16 acc[2][2] = {};
    #pragma unroll
    for (int kk = 0; kk < 4; ++kk) {
        short8 a0 = *reinterpret_cast<const short8*>(&A_lds[wm*2 + 0][kk][lane][0]);
        short8 a1 = *reinterpret_cast<const short8*>(&A_lds[wm*2 + 1][kk][lane][0]);
        acc[0][0] = __builtin_amdgcn_mfma_f32_32x32x16_bf16(a0, bf[0][kk], acc[0][0], 0, 0, 0);
        acc[0][1] = __builtin_amdgcn_mfma_f32_32x32x16_bf16(a0, bf[1][kk], acc[0][1], 0, 0, 0);
        acc[1][0] = __builtin_amdgcn_mfma_f32_32x32x16_bf16(a1, bf[0][kk], acc[1][0], 0, 0, 0);
        acc[1][1] = __builtin_amdgcn_mfma_f32_32x32x16_bf16(a1, bf[1][kk], acc[1][1], 0, 0, 0);
    }

    // ---- epilogue: sq = lsq[row] + rsq[col] - 2*dot, balanced max tree ----
    // C layout (32x32): col = lane&31, row = (r&3) + 8*(r>>2) + 4*(lane>>5)
    float lmax = 0.f;
    #pragma unroll
    for (int mi = 0; mi < 2; ++mi) {
        const int rbase = xc * 128 + (wm * 2 + mi) * 32 + 4 * h;
        f32x4 lq0 = *reinterpret_cast<const f32x4*>(lsq + rbase +  0);
        f32x4 lq1 = *reinterpret_cast<const f32x4*>(lsq + rbase +  8);
        f32x4 lq2 = *reinterpret_cast<const f32x4*>(lsq + rbase + 16);
        f32x4 lq3 = *reinterpret_cast<const f32x4*>(lsq + rbase + 24);
        #pragma unroll
        for (int nj = 0; nj < 2; ++nj) {
            float x[16];
            #pragma unroll
            for (int e = 0; e < 4; ++e) {
                x[0  + e] = fmaf(-2.f, acc[mi][nj][0  + e], lq0[e]);
                x[4  + e] = fmaf(-2.f, acc[mi][nj][4  + e], lq1[e]);
                x[8  + e] = fmaf(-2.f, acc[mi][nj][8  + e], lq2[e]);
                x[12 + e] = fmaf(-2.f, acc[mi][nj][12 + e], lq3[e]);
            }
            float y0 = fmaxf(x[0],  x[1]),  y1 = fmaxf(x[2],  x[3]);
            float y2 = fmaxf(x[4],  x[5]),  y3 = fmaxf(x[6],  x[7]);
            float y4 = fmaxf(x[8],  x[9]),  y5 = fmaxf(x[10], x[11]);
            float y6 = fmaxf(x[12], x[13]), y7 = fmaxf(x[14], x[15]);
            float z0 = fmaxf(y0, y1), z1 = fmaxf(y2, y3);
            float z2 = fmaxf(y4, y5), z3 = fmaxf(y6, y7);
            float m  = fmaxf(fmaxf(z0, z1), fmaxf(z2, z3));
            lmax = fmaxf(lmax, m + rq[nj]);
        }
    }

    // ---- tail: wave butterfly, tiny LDS reduce, one atomic ----
    #pragma unroll
    for (int off = 32; off >= 1; off >>= 1)
        lmax = fmaxf(lmax, __shfl_xor(lmax, off, 64));
    if (lane == 0) wmax_s[wave] = lmax;
    __syncthreads();
    if (tid == 0) {
        float bmax = fmaxf(fmaxf(wmax_s[0], wmax_s[1]), fmaxf(wmax_s[2], wmax_s[3]));
        bmax = sqrtf(fmaxf(bmax, 0.f));            // sqrt monotone
        atomicMax(outbits, __float_as_uint(bmax)); // uint order == float order, >=0
    }
}

extern "C" void kernel_launch(void* const* d_in, const int* in_sizes, int n_in,
                              void* d_out, int out_size, void* d_ws, size_t ws_size,
                              hipStream_t stream) {
    const float* L = (const float*)d_in[0];
    const float* R = (const float*)d_in[1];

    short* Apk = (short*)d_ws;
    short* Bpk = Apk + (size_t)NR * D;           // 524288 shorts each
    float* lsqg = (float*)(Bpk + (size_t)NR * D);
    float* rsqg = lsqg + NR;
    unsigned int* outbits = (unsigned int*)d_out;

    prepack_kernel<<<(2 * NR * 8) / 256, 256, 0, stream>>>(L, R, Apk, Bpk, lsqg, rsqg, outbits);
    pairdist_mfma_kernel<<<4096, 256, 0, stream>>>(Apk, Bpk, lsqg, rsqg, outbits);
}

// Round 13
// 25.417 us; speedup vs baseline: 2.6424x; 2.3747x over previous
//
#include <hip/hip_runtime.h>
#include <hip/hip_bf16.h>
#include <math.h>

// max_{n,m} ||L[n]-R[m]||, L,R: [8192][64] fp32.
// R13: R12 compute verbatim, but NO same-address atomics (R12's 52us dispatch
// at <10% pipe util == 4096 serialized RMWs ~30cyc each ~= 51us). Tail is a
// contention-free slots[bid] store; tiny finalize kernel reduces 4096 slots.

typedef __attribute__((ext_vector_type(8)))  short  short8;   // bf16x8 frag
typedef __attribute__((ext_vector_type(4)))  float  f32x4;
typedef __attribute__((ext_vector_type(16))) float  f32x16;   // 32x32 accum

constexpr int D  = 64;
constexpr int NR = 8192;
constexpr int NBLK = 4096;

__device__ __forceinline__ short f2bf(float f) {
    __hip_bfloat16 h = __float2bfloat16(f);
    return __builtin_bit_cast(short, h);
}

// Frag-packed layout: row r, k-chunk kk (16 k's), k-half kh, elem e:
//   short index = ((r>>5)*4 + kk)*512 + (kh*32 + (r&31))*8 + e

__global__ __launch_bounds__(256) void prepack_kernel(
    const float* __restrict__ L, const float* __restrict__ R,
    short* __restrict__ Apk, short* __restrict__ Bpk,
    float* __restrict__ lsq, float* __restrict__ rsq)
{
    const int t = blockIdx.x * 256 + threadIdx.x;   // 0..131071
    const int r = t >> 3;
    const int j = t & 7;
    const int kk = j >> 1, kh = j & 1;
    const bool isL = (r < NR);
    const int rr = isL ? r : r - NR;

    const float* src = (isL ? L : R) + (size_t)rr * D + j * 8;
    short* pk = isL ? Apk : Bpk;

    f32x4 v0 = *reinterpret_cast<const f32x4*>(src + 0);
    f32x4 v1 = *reinterpret_cast<const f32x4*>(src + 4);

    float p = 0.f;
    #pragma unroll
    for (int e = 0; e < 4; ++e) { p = fmaf(v0[e], v0[e], p); p = fmaf(v1[e], v1[e], p); }

    short8 w;
    #pragma unroll
    for (int e = 0; e < 4; ++e) { w[e] = f2bf(v0[e]); w[4+e] = f2bf(v1[e]); }
    *reinterpret_cast<short8*>(
        pk + ((size_t)(rr >> 5) * 4 + kk) * 512 + (kh * 32 + (rr & 31)) * 8) = w;

    p += __shfl_xor(p, 1, 64);
    p += __shfl_xor(p, 2, 64);
    p += __shfl_xor(p, 4, 64);
    if (j == 0) (isL ? lsq : rsq)[rr] = p;
}

// ---- main: 4 waves (2m x 2n), block 128m x 128n one-shot ----
// grid 4096 1-D: xc = bid & 63 (rows), yb = bid >> 6 (cols).
// Same-xc blocks share bid%8 -> same XCD under round-robin (A chunk in L2).
__global__ __launch_bounds__(256, 4) void pairdist_mfma_kernel(
    const short* __restrict__ Apk, const short* __restrict__ Bpk,
    const float* __restrict__ lsq, const float* __restrict__ rsq,
    float* __restrict__ slots)
{
    __shared__ __align__(16) short A_lds[4][4][64][8];   // 16 KiB (128 rows)
    __shared__ float wmax_s[4];

    const int tid  = threadIdx.x;
    const int lane = tid & 63;
    const int wave = tid >> 6;
    const int bid  = blockIdx.x;
    const int xc = bid & 63;       // row chunk (128 rows)
    const int yb = bid >> 6;       // col chunk (128 cols)

    // ---- stage A (16 x 1KB global_load_lds): wave = kk, i = row group ----
    {
        const short* At = Apk + (size_t)(xc * 4) * 2048;
        #pragma unroll
        for (int i = 0; i < 4; ++i)
            __builtin_amdgcn_global_load_lds(
                (const __attribute__((address_space(1))) unsigned int*)
                    (At + ((size_t)i * 4 + wave) * 512 + lane * 8),
                (__attribute__((address_space(3))) unsigned int*)
                    (&A_lds[i][wave][0][0]),
                16, 0, 0);
    }

    const int wm = wave >> 1;      // 64-row half of 128
    const int wn = wave & 1;       // 64-col half of 128
    // ---- B-frags (2 col groups x 4 kk = 8 dwordx4, 32 VGPR) ----
    short8 bf[2][4];
    #pragma unroll
    for (int nj = 0; nj < 2; ++nj)
        #pragma unroll
        for (int kk = 0; kk < 4; ++kk)
            bf[nj][kk] = *reinterpret_cast<const short8*>(
                Bpk + ((size_t)(yb * 4 + wn * 2 + nj) * 4 + kk) * 512 + lane * 8);

    const int col = lane & 31;
    const int h   = lane >> 5;
    float rq[2];
    #pragma unroll
    for (int nj = 0; nj < 2; ++nj)
        rq[nj] = rsq[yb * 128 + (wn * 2 + nj) * 32 + col];

    __syncthreads();   // A staged (vmcnt drained by compiler)

    // ---- MFMA: acc[2][2] (64 AGPR), 16 MFMAs ----
    f32x16 acc[2][2] = {};
    #pragma unroll
    for (int kk = 0; kk < 4; ++kk) {
        short8 a0 = *reinterpret_cast<const short8*>(&A_lds[wm*2 + 0][kk][lane][0]);
        short8 a1 = *reinterpret_cast<const short8*>(&A_lds[wm*2 + 1][kk][lane][0]);
        acc[0][0] = __builtin_amdgcn_mfma_f32_32x32x16_bf16(a0, bf[0][kk], acc[0][0], 0, 0, 0);
        acc[0][1] = __builtin_amdgcn_mfma_f32_32x32x16_bf16(a0, bf[1][kk], acc[0][1], 0, 0, 0);
        acc[1][0] = __builtin_amdgcn_mfma_f32_32x32x16_bf16(a1, bf[0][kk], acc[1][0], 0, 0, 0);
        acc[1][1] = __builtin_amdgcn_mfma_f32_32x32x16_bf16(a1, bf[1][kk], acc[1][1], 0, 0, 0);
    }

    // ---- epilogue: sq = lsq[row] + rsq[col] - 2*dot, balanced max tree ----
    // C layout (32x32): col = lane&31, row = (r&3) + 8*(r>>2) + 4*(lane>>5)
    float lmax = 0.f;
    #pragma unroll
    for (int mi = 0; mi < 2; ++mi) {
        const int rbase = xc * 128 + (wm * 2 + mi) * 32 + 4 * h;
        f32x4 lq0 = *reinterpret_cast<const f32x4*>(lsq + rbase +  0);
        f32x4 lq1 = *reinterpret_cast<const f32x4*>(lsq + rbase +  8);
        f32x4 lq2 = *reinterpret_cast<const f32x4*>(lsq + rbase + 16);
        f32x4 lq3 = *reinterpret_cast<const f32x4*>(lsq + rbase + 24);
        #pragma unroll
        for (int nj = 0; nj < 2; ++nj) {
            float x[16];
            #pragma unroll
            for (int e = 0; e < 4; ++e) {
                x[0  + e] = fmaf(-2.f, acc[mi][nj][0  + e], lq0[e]);
                x[4  + e] = fmaf(-2.f, acc[mi][nj][4  + e], lq1[e]);
                x[8  + e] = fmaf(-2.f, acc[mi][nj][8  + e], lq2[e]);
                x[12 + e] = fmaf(-2.f, acc[mi][nj][12 + e], lq3[e]);
            }
            float y0 = fmaxf(x[0],  x[1]),  y1 = fmaxf(x[2],  x[3]);
            float y2 = fmaxf(x[4],  x[5]),  y3 = fmaxf(x[6],  x[7]);
            float y4 = fmaxf(x[8],  x[9]),  y5 = fmaxf(x[10], x[11]);
            float y6 = fmaxf(x[12], x[13]), y7 = fmaxf(x[14], x[15]);
            float z0 = fmaxf(y0, y1), z1 = fmaxf(y2, y3);
            float z2 = fmaxf(y4, y5), z3 = fmaxf(y6, y7);
            float m  = fmaxf(fmaxf(z0, z1), fmaxf(z2, z3));
            lmax = fmaxf(lmax, m + rq[nj]);
        }
    }

    // ---- tail: wave butterfly, tiny LDS reduce, ONE PLAIN STORE ----
    #pragma unroll
    for (int off = 32; off >= 1; off >>= 1)
        lmax = fmaxf(lmax, __shfl_xor(lmax, off, 64));
    if (lane == 0) wmax_s[wave] = lmax;
    __syncthreads();
    if (tid == 0) {
        float bmax = fmaxf(fmaxf(wmax_s[0], wmax_s[1]), fmaxf(wmax_s[2], wmax_s[3]));
        slots[bid] = fmaxf(bmax, 0.f);   // contention-free
    }
}

// ---- finalize: reduce 4096 slots, sqrt, write scalar ----
__global__ __launch_bounds__(512) void finalize_kernel(
    const float* __restrict__ slots, float* __restrict__ out)
{
    __shared__ float wred[8];
    const int tid = threadIdx.x;
    float v = -3.0e38f;
    #pragma unroll
    for (int i = 0; i < NBLK / 512; ++i)
        v = fmaxf(v, slots[tid + i * 512]);
    #pragma unroll
    for (int off = 32; off >= 1; off >>= 1)
        v = fmaxf(v, __shfl_xor(v, off, 64));
    if ((tid & 63) == 0) wred[tid >> 6] = v;
    __syncthreads();
    if (tid == 0) {
        float m = wred[0];
        #pragma unroll
        for (int i = 1; i < 8; ++i) m = fmaxf(m, wred[i]);
        out[0] = sqrtf(m);
    }
}

extern "C" void kernel_launch(void* const* d_in, const int* in_sizes, int n_in,
                              void* d_out, int out_size, void* d_ws, size_t ws_size,
                              hipStream_t stream) {
    const float* L = (const float*)d_in[0];
    const float* R = (const float*)d_in[1];

    short* Apk = (short*)d_ws;
    short* Bpk = Apk + (size_t)NR * D;           // 524288 shorts each
    float* lsqg = (float*)(Bpk + (size_t)NR * D);
    float* rsqg = lsqg + NR;
    float* slots = rsqg + NR;

    prepack_kernel<<<(2 * NR * 8) / 256, 256, 0, stream>>>(L, R, Apk, Bpk, lsqg, rsqg);
    pairdist_mfma_kernel<<<NBLK, 256, 0, stream>>>(Apk, Bpk, lsqg, rsqg, slots);
    finalize_kernel<<<1, 512, 0, stream>>>(slots, (float*)d_out);
}